// Round 2
// baseline (760.695 us; speedup 1.0000x reference)
//
#include <hip/hip_runtime.h>

#define BB 32
#define CC 64
#define C2 32
#define HH 56
#define WW 56
#define HW 3136

// ---------------- lepe: depthwise 7x7 conv + bias + bn -> d_out ----------------
// 4 consecutive pixels per thread; aligned float4 window loads (row stride 224B, 16B-aligned).
__global__ __launch_bounds__(256) void lepe_k(const float* __restrict__ x,
                                              const float* __restrict__ wt,
                                              const float* __restrict__ b,
                                              const float* __restrict__ s,
                                              const float* __restrict__ bb,
                                              float* __restrict__ out) {
    const int t = blockIdx.x * 256 + threadIdx.x;      // 2048*784 threads exactly
    const int q = t % 784;
    const int bc = t / 784;
    const int c = bc & 63;
    const int r = q / 14;
    const int c4 = (q % 14) * 4;
    const float* xp = x + (long)bc * HW;
    float acc0 = 0.f, acc1 = 0.f, acc2 = 0.f, acc3 = 0.f;
    #pragma unroll
    for (int i = 0; i < 7; ++i) {
        const int y = r + i - 3;
        if ((unsigned)y >= HH) continue;
        float w7[7];
        #pragma unroll
        for (int j = 0; j < 7; ++j) w7[j] = wt[c * 49 + i * 7 + j];
        const float4* row = reinterpret_cast<const float4*>(xp + y * WW + c4 - 4);
        float4 A = make_float4(0.f, 0.f, 0.f, 0.f);
        float4 Cv = make_float4(0.f, 0.f, 0.f, 0.f);
        if (c4 != 0) A = row[0];
        const float4 Bv = row[1];
        if (c4 != 52) Cv = row[2];
        const float w12[12] = {A.x, A.y, A.z, A.w, Bv.x, Bv.y, Bv.z, Bv.w, Cv.x, Cv.y, Cv.z, Cv.w};
        #pragma unroll
        for (int j = 0; j < 7; ++j) {
            acc0 = fmaf(w12[j + 1], w7[j], acc0);
            acc1 = fmaf(w12[j + 2], w7[j], acc1);
            acc2 = fmaf(w12[j + 3], w7[j], acc2);
            acc3 = fmaf(w12[j + 4], w7[j], acc3);
        }
    }
    const float bc_ = b[c], sc = s[c], bbc = bb[c];
    float* op = out + (long)bc * HW + r * WW + c4;
    op[0] = (acc0 + bc_) * sc + bbc;
    op[1] = (acc1 + bc_) * sc + bbc;
    op[2] = (acc2 + bc_) * sc + bbc;
    op[3] = (acc3 + bc_) * sc + bbc;
}

// ---------------- q: 32x32 channel matmul + bn, *SCALE ----------------
__global__ __launch_bounds__(256) void q_k(const float* __restrict__ x,
                                           const float* __restrict__ wq,
                                           const float* __restrict__ s,
                                           const float* __restrict__ bb,
                                           float* __restrict__ q) {
    __shared__ float wsm[32 * 32];      // transposed: wsm[i*32+o] = wq[o*32+i]
    const int b = blockIdx.y;
    const int tid = threadIdx.x;
    for (int i = tid; i < 1024; i += 256) wsm[(i & 31) * 32 + (i >> 5)] = wq[i];
    __syncthreads();
    const int n = blockIdx.x * 256 + tid;
    if (n >= HW) return;
    const float* xp = x + (long)b * CC * HW;   // first 32 channels
    float acc[32];
    #pragma unroll
    for (int o = 0; o < 32; ++o) acc[o] = 0.f;
    for (int i = 0; i < 32; ++i) {
        const float xv = xp[i * HW + n];
        #pragma unroll
        for (int o = 0; o < 32; ++o) acc[o] = fmaf(wsm[i * 32 + o], xv, acc[o]);
    }
    float* qp = q + (long)b * C2 * HW + n;
    #pragma unroll
    for (int o = 0; o < 32; ++o)
        qp[o * HW] = (acc[o] * s[o] + bb[o]) * 0.25f;
}

// ---------------- prep: pool(8x8 mean) -> wk matmul+bn -> WK = wp * kg^T ----------------
// One block per batch b. WK[bg][c][76] with m-pad zeroed.
__global__ __launch_bounds__(256) void prep_k(const float* __restrict__ x,
                                              const float* __restrict__ wk,
                                              const float* __restrict__ wks,
                                              const float* __restrict__ wkb,
                                              const float* __restrict__ wp_w,
                                              float* __restrict__ WK) {
    __shared__ float p_s[32 * 49];
    __shared__ float kg_s[32 * 49];
    const int b = blockIdx.x;
    const int tid = threadIdx.x;
    for (int idx = tid; idx < 1568; idx += 256) {
        const int i = idx / 49, l = idx % 49;
        const int py = l / 7, px = l % 7;
        const float* xp = x + ((long)(b * CC + 32 + i)) * HW + py * 8 * WW + px * 8;
        float acc = 0.f;
        #pragma unroll
        for (int y = 0; y < 8; ++y)
            #pragma unroll
            for (int xx = 0; xx < 8; ++xx) acc += xp[y * WW + xx];
        p_s[idx] = acc * (1.f / 64.f);
    }
    __syncthreads();
    for (int idx = tid; idx < 1568; idx += 256) {
        const int o = idx / 49, l = idx % 49;
        float acc = 0.f;
        #pragma unroll
        for (int i = 0; i < 32; ++i) acc = fmaf(wk[o * 32 + i], p_s[i * 49 + l], acc);
        kg_s[idx] = acc * wks[o] + wkb[o];
    }
    __syncthreads();
    for (int idx = tid; idx < 2432; idx += 256) {
        const int g = idx / 608;
        const int rr = idx % 608;
        const int c = rr / 76, m = rr % 76;
        float acc = 0.f;
        if (m < 74) {
            const float* kp = kg_s + (g * 8 + c) * 49;
            #pragma unroll
            for (int l = 0; l < 49; ++l) acc = fmaf(wp_w[m * 49 + l], kp[l], acc);
        }
        WK[((long)b * 4 + g) * 608 + c * 76 + m] = acc;
    }
}

// ---------------- fused attention (q -> wm via WK -> +rpb -> softmax) + dyn_mix ----------------
__global__ __launch_bounds__(256) void attnmix_k(const float* __restrict__ x,
                                                 const float* __restrict__ q,
                                                 const float* __restrict__ WK,
                                                 const float* __restrict__ wp_b,
                                                 const float* __restrict__ rpb1,
                                                 const float* __restrict__ rpb2,
                                                 float* __restrict__ mix) {
    __shared__ float WK_s[608];         // [c][76], m-pad zeroed by prep
    __shared__ float wpb_s[74];
    __shared__ float rpb1_s[81];
    __shared__ float rpb2_s[169];
    const int tid = threadIdx.x;
    const int bg = blockIdx.y;
    const int g = bg & 3, b = bg >> 2;
    for (int i = tid; i < 608; i += 256) WK_s[i] = WK[(long)bg * 608 + i];
    if (tid < 74) wpb_s[tid] = wp_b[tid];
    if (tid < 81) rpb1_s[tid] = rpb1[g * 81 + tid];
    if (tid < 169) rpb2_s[tid] = rpb2[g * 169 + tid];
    __syncthreads();
    const int n = blockIdx.x * 256 + tid;
    if (n >= HW) return;

    float q8[8];
    #pragma unroll
    for (int c = 0; c < 8; ++c) q8[c] = q[((long)b * C2 + g * 8 + c) * HW + n];

    // wm[m] = wp_b[m] + sum_c q8[c] * WK[m][c]      (re-associated: WK = wp * kg^T)
    float wm[74];
    #pragma unroll
    for (int m = 0; m < 74; ++m) wm[m] = wpb_s[m];
    #pragma unroll
    for (int c = 0; c < 8; ++c) {
        const float qv = q8[c];
        #pragma unroll
        for (int m = 0; m < 74; ++m) wm[m] = fmaf(qv, WK_s[c * 76 + m], wm[m]);
    }

    // relative position bias (reversed-index formula)
    const int ph = n / WW, pw = n % WW;
    const int yr = HH - 1 - ph, xr = WW - 1 - pw;
    const int rh5 = yr < 2 ? yr : (yr > 53 ? yr - 51 : 2);
    const int rw5 = xr < 2 ? xr : (xr > 53 ? xr - 51 : 2);
    const int rh7 = yr < 3 ? yr : (yr > 52 ? yr - 49 : 3);
    const int rw7 = xr < 3 ? xr : (xr > 52 ? xr - 49 : 3);
    #pragma unroll
    for (int i = 0; i < 5; ++i)
        #pragma unroll
        for (int j = 0; j < 5; ++j)
            wm[i * 5 + j] += rpb1_s[(rh5 + i) * 9 + (rw5 + j)];
    #pragma unroll
    for (int i = 0; i < 7; ++i)
        #pragma unroll
        for (int j = 0; j < 7; ++j)
            wm[25 + i * 7 + j] += rpb2_s[(rh7 + i) * 13 + (rw7 + j)];

    // dual softmax
    float mx1 = -1e30f, mx2 = -1e30f;
    #pragma unroll
    for (int m = 0; m < 25; ++m) mx1 = fmaxf(mx1, wm[m]);
    #pragma unroll
    for (int m = 25; m < 74; ++m) mx2 = fmaxf(mx2, wm[m]);
    float s1 = 0.f, s2 = 0.f;
    #pragma unroll
    for (int m = 0; m < 25; ++m) { wm[m] = __expf(wm[m] - mx1); s1 += wm[m]; }
    #pragma unroll
    for (int m = 25; m < 74; ++m) { wm[m] = __expf(wm[m] - mx2); s2 += wm[m]; }
    const float r1 = 1.f / s1, r2 = 1.f / s2;
    #pragma unroll
    for (int m = 0; m < 25; ++m) wm[m] *= r1;
    #pragma unroll
    for (int m = 25; m < 74; ++m) wm[m] *= r2;

    // dynamic mix: 5x5 over v0 (ch 0..31), 7x7 over v1 (ch 32..63)
    const float* v0 = x + ((long)b * CC + g * 8) * HW;
    const float* v1 = x + ((long)b * CC + 32 + g * 8) * HW;
    float* m0 = mix + ((long)b * CC + g * 8) * HW + n;
    float* m1 = mix + ((long)b * CC + 32 + g * 8) * HW + n;
    #pragma unroll
    for (int ch = 0; ch < 8; ++ch) {
        float a1 = 0.f;
        #pragma unroll
        for (int i = 0; i < 5; ++i) {
            const int y = ph + i - 2;
            if (y < 0 || y >= HH) continue;
            #pragma unroll
            for (int j = 0; j < 5; ++j) {
                const int xx = pw + j - 2;
                if (xx < 0 || xx >= WW) continue;
                a1 = fmaf(wm[i * 5 + j], v0[ch * HW + y * WW + xx], a1);
            }
        }
        m0[ch * HW] = a1;
        float a2 = 0.f;
        #pragma unroll
        for (int i = 0; i < 7; ++i) {
            const int y = ph + i - 3;
            if (y < 0 || y >= HH) continue;
            #pragma unroll
            for (int j = 0; j < 7; ++j) {
                const int xx = pw + j - 3;
                if (xx < 0 || xx >= WW) continue;
                a2 = fmaf(wm[25 + i * 7 + j], v1[ch * HW + y * WW + xx], a2);
            }
        }
        m1[ch * HW] = a2;
    }
}

// ---------------- final: 64x64 channel matmul + bn + lepe add ----------------
// register-tiled: each thread owns 2 pixels x 32 outputs.
__global__ __launch_bounds__(256) void final_k(const float* __restrict__ mix,
                                               const float* __restrict__ dy_w,
                                               const float* __restrict__ s,
                                               const float* __restrict__ bb,
                                               float* __restrict__ out) {
    __shared__ float w_s[64 * 64];      // transposed: w_s[i*64+o] = dy_w[o*64+i]
    const int tid = threadIdx.x;
    const int b = blockIdx.y;
    for (int i = tid; i < 4096; i += 256) w_s[(i & 63) * 64 + (i >> 6)] = dy_w[i];
    __syncthreads();
    const int ob = (tid >> 7) * 32;                 // wave-uniform output half
    const int p0 = blockIdx.x * 256 + (tid & 127);
    const int p1 = p0 + 128;
    const bool v0 = p0 < HW, v1 = p1 < HW;
    const float* mp = mix + (long)b * CC * HW;
    float acc0[32], acc1[32];
    #pragma unroll
    for (int o = 0; o < 32; ++o) { acc0[o] = 0.f; acc1[o] = 0.f; }
    for (int i = 0; i < 64; ++i) {
        const float mv0 = v0 ? mp[i * HW + p0] : 0.f;
        const float mv1 = v1 ? mp[i * HW + p1] : 0.f;
        const float* wr = w_s + i * 64 + ob;
        #pragma unroll
        for (int o = 0; o < 32; ++o) {
            const float wv = wr[o];
            acc0[o] = fmaf(wv, mv0, acc0[o]);
            acc1[o] = fmaf(wv, mv1, acc1[o]);
        }
    }
    float* op = out + (long)b * CC * HW;
    if (v0) {
        #pragma unroll
        for (int o = 0; o < 32; ++o) {
            const long idx = (long)(ob + o) * HW + p0;
            op[idx] = fmaf(acc0[o], s[ob + o], bb[ob + o]) + op[idx];
        }
    }
    if (v1) {
        #pragma unroll
        for (int o = 0; o < 32; ++o) {
            const long idx = (long)(ob + o) * HW + p1;
            op[idx] = fmaf(acc1[o], s[ob + o], bb[ob + o]) + op[idx];
        }
    }
}

extern "C" void kernel_launch(void* const* d_in, const int* in_sizes, int n_in,
                              void* d_out, int out_size, void* d_ws, size_t ws_size,
                              hipStream_t stream) {
    const float* x       = (const float*)d_in[0];
    const float* lepe_w  = (const float*)d_in[1];
    const float* lepe_b  = (const float*)d_in[2];
    const float* lepe_s  = (const float*)d_in[3];
    const float* lepe_bb = (const float*)d_in[4];
    const float* wq_w    = (const float*)d_in[5];
    const float* wq_s    = (const float*)d_in[6];
    const float* wq_bb   = (const float*)d_in[7];
    const float* wk_w    = (const float*)d_in[8];
    const float* wk_s    = (const float*)d_in[9];
    const float* wk_bb   = (const float*)d_in[10];
    const float* wp_w    = (const float*)d_in[11];
    const float* wp_b    = (const float*)d_in[12];
    const float* rpb1    = (const float*)d_in[13];
    const float* rpb2    = (const float*)d_in[14];
    const float* dy_w    = (const float*)d_in[15];
    const float* dy_s    = (const float*)d_in[16];
    const float* dy_bb   = (const float*)d_in[17];
    float* out = (float*)d_out;

    float* ws     = (float*)d_ws;
    float* q_ws   = ws;                               // 32*32*3136 = 3211264
    float* WK_ws  = q_ws + 32 * 32 * HW;              // 128*608    = 77824
    float* mix_ws = WK_ws + 128 * 608;                // 32*64*3136 = 6422528

    const int nTiles = (HW + 255) / 256;              // 13

    lepe_k<<<dim3(2048 * 784 / 256), 256, 0, stream>>>(x, lepe_w, lepe_b, lepe_s, lepe_bb, out);
    q_k<<<dim3(nTiles, BB), 256, 0, stream>>>(x, wq_w, wq_s, wq_bb, q_ws);
    prep_k<<<dim3(BB), 256, 0, stream>>>(x, wk_w, wk_s, wk_bb, wp_w, WK_ws);
    attnmix_k<<<dim3(nTiles, BB * 4), 256, 0, stream>>>(x, q_ws, WK_ws, wp_b, rpb1, rpb2, mix_ws);
    final_k<<<dim3(nTiles, BB), 256, 0, stream>>>(mix_ws, dy_w, dy_s, dy_bb, out);
}

// Round 3
// 439.470 us; speedup vs baseline: 1.7309x; 1.7309x over previous
//
#include <hip/hip_runtime.h>

#define BB 32
#define CC 64
#define C2 32
#define HH 56
#define WW 56
#define HW 3136

// ---------------- lepe: depthwise 7x7 conv + bias + bn -> d_out ----------------
__global__ __launch_bounds__(256) void lepe_k(const float* __restrict__ x,
                                              const float* __restrict__ wt,
                                              const float* __restrict__ b,
                                              const float* __restrict__ s,
                                              const float* __restrict__ bb,
                                              float* __restrict__ out) {
    const int t = blockIdx.x * 256 + threadIdx.x;      // 2048*784 threads exactly
    const int q = t % 784;
    const int bc = t / 784;
    const int c = bc & 63;
    const int r = q / 14;
    const int c4 = (q % 14) * 4;
    const float* xp = x + (long)bc * HW;
    float acc0 = 0.f, acc1 = 0.f, acc2 = 0.f, acc3 = 0.f;
    #pragma unroll
    for (int i = 0; i < 7; ++i) {
        const int y = r + i - 3;
        if ((unsigned)y >= HH) continue;
        float w7[7];
        #pragma unroll
        for (int j = 0; j < 7; ++j) w7[j] = wt[c * 49 + i * 7 + j];
        const float4* row = reinterpret_cast<const float4*>(xp + y * WW + c4 - 4);
        float4 A = make_float4(0.f, 0.f, 0.f, 0.f);
        float4 Cv = make_float4(0.f, 0.f, 0.f, 0.f);
        if (c4 != 0) A = row[0];
        const float4 Bv = row[1];
        if (c4 != 52) Cv = row[2];
        const float w12[12] = {A.x, A.y, A.z, A.w, Bv.x, Bv.y, Bv.z, Bv.w, Cv.x, Cv.y, Cv.z, Cv.w};
        #pragma unroll
        for (int j = 0; j < 7; ++j) {
            acc0 = fmaf(w12[j + 1], w7[j], acc0);
            acc1 = fmaf(w12[j + 2], w7[j], acc1);
            acc2 = fmaf(w12[j + 3], w7[j], acc2);
            acc3 = fmaf(w12[j + 4], w7[j], acc3);
        }
    }
    const float bc_ = b[c], sc = s[c], bbc = bb[c];
    float* op = out + (long)bc * HW + r * WW + c4;
    op[0] = (acc0 + bc_) * sc + bbc;
    op[1] = (acc1 + bc_) * sc + bbc;
    op[2] = (acc2 + bc_) * sc + bbc;
    op[3] = (acc3 + bc_) * sc + bbc;
}

// ---------------- q: 32x32 channel matmul + bn, *SCALE ----------------
__global__ __launch_bounds__(256) void q_k(const float* __restrict__ x,
                                           const float* __restrict__ wq,
                                           const float* __restrict__ s,
                                           const float* __restrict__ bb,
                                           float* __restrict__ q) {
    __shared__ float wsm[32 * 32];      // transposed: wsm[i*32+o] = wq[o*32+i]
    const int b = blockIdx.y;
    const int tid = threadIdx.x;
    for (int i = tid; i < 1024; i += 256) wsm[(i & 31) * 32 + (i >> 5)] = wq[i];
    __syncthreads();
    const int n = blockIdx.x * 256 + tid;
    if (n >= HW) return;
    const float* xp = x + (long)b * CC * HW;   // first 32 channels
    float acc[32];
    #pragma unroll
    for (int o = 0; o < 32; ++o) acc[o] = 0.f;
    for (int i = 0; i < 32; ++i) {
        const float xv = xp[i * HW + n];
        #pragma unroll
        for (int o = 0; o < 32; ++o) acc[o] = fmaf(wsm[i * 32 + o], xv, acc[o]);
    }
    float* qp = q + (long)b * C2 * HW + n;
    #pragma unroll
    for (int o = 0; o < 32; ++o)
        qp[o * HW] = (acc[o] * s[o] + bb[o]) * 0.25f;
}

// ---------------- prep: pool(8x8 mean) -> wk matmul+bn -> WK = wp * kg^T ----------------
// One block per batch b. Output per bg: WK1[c][28] (25 used) then WK2[c][52] (49 used),
// zero-padded, 640 floats per bg.
__global__ __launch_bounds__(256) void prep_k(const float* __restrict__ x,
                                              const float* __restrict__ wk,
                                              const float* __restrict__ wks,
                                              const float* __restrict__ wkb,
                                              const float* __restrict__ wp_w,
                                              float* __restrict__ WK) {
    __shared__ float p_s[32 * 49];
    __shared__ float kg_s[32 * 49];
    const int b = blockIdx.x;
    const int tid = threadIdx.x;
    for (int idx = tid; idx < 1568; idx += 256) {
        const int i = idx / 49, l = idx % 49;
        const int py = l / 7, px = l % 7;
        const float* xp = x + ((long)(b * CC + 32 + i)) * HW + py * 8 * WW + px * 8;
        float acc = 0.f;
        #pragma unroll
        for (int y = 0; y < 8; ++y)
            #pragma unroll
            for (int xx = 0; xx < 8; ++xx) acc += xp[y * WW + xx];
        p_s[idx] = acc * (1.f / 64.f);
    }
    __syncthreads();
    for (int idx = tid; idx < 1568; idx += 256) {
        const int o = idx / 49, l = idx % 49;
        float acc = 0.f;
        #pragma unroll
        for (int i = 0; i < 32; ++i) acc = fmaf(wk[o * 32 + i], p_s[i * 49 + l], acc);
        kg_s[idx] = acc * wks[o] + wkb[o];
    }
    __syncthreads();
    // 4 groups * 8 c * 80 slots (28 for attn1, 52 for attn2) = 2560 per batch
    for (int idx = tid; idx < 2560; idx += 256) {
        const int g = idx / 640;
        const int rr = idx % 640;
        const int c = rr / 80, slot = rr % 80;
        float acc = 0.f;
        int m = -1;
        if (slot < 28) { if (slot < 25) m = slot; }
        else           { if (slot < 77) m = 25 + (slot - 28); }
        if (m >= 0) {
            const float* kp = kg_s + (g * 8 + c) * 49;
            #pragma unroll
            for (int l = 0; l < 49; ++l) acc = fmaf(wp_w[m * 49 + l], kp[l], acc);
        }
        // layout per bg: WK1 region [c*28 + slot] then WK2 region [224 + c*52 + (slot-28)]
        const long base = ((long)b * 4 + g) * 640;
        if (slot < 28) WK[base + c * 28 + slot] = acc;
        else           WK[base + 224 + c * 52 + (slot - 28)] = acc;
    }
}

// ---------------- fused attention (q -> wm via WK -> +rpb -> softmax) + dyn_mix ----------------
// Two independent phases (25-weight / 49-weight) processed sequentially to cap live registers.
__global__ __launch_bounds__(256) void attnmix_k(const float* __restrict__ x,
                                                 const float* __restrict__ q,
                                                 const float* __restrict__ WK,
                                                 const float* __restrict__ wp_b,
                                                 const float* __restrict__ rpb1,
                                                 const float* __restrict__ rpb2,
                                                 float* __restrict__ mix) {
    __shared__ float WK1_s[8 * 28];     // [c][28], pad zeroed
    __shared__ float WK2_s[8 * 52];     // [c][52], pad zeroed
    __shared__ float wpb1_s[25];
    __shared__ float wpb2_s[49];
    __shared__ float rpb1_s[81];
    __shared__ float rpb2_s[169];
    const int tid = threadIdx.x;
    const int bg = blockIdx.y;
    const int g = bg & 3, b = bg >> 2;
    {
        const float* wkp = WK + (long)bg * 640;
        for (int i = tid; i < 224; i += 256) WK1_s[i] = wkp[i];
        for (int i = tid; i < 416; i += 256) WK2_s[i] = wkp[224 + i];
    }
    if (tid < 25) wpb1_s[tid] = wp_b[tid];
    if (tid >= 32 && tid < 81) wpb2_s[tid - 32] = wp_b[25 + tid - 32];
    if (tid < 81) rpb1_s[tid] = rpb1[g * 81 + tid];
    if (tid < 169) rpb2_s[tid] = rpb2[g * 169 + tid];
    __syncthreads();
    const int n = blockIdx.x * 256 + tid;
    if (n >= HW) return;

    const int ph = n / WW, pw = n % WW;
    const int yr = HH - 1 - ph, xr = WW - 1 - pw;

    float q8[8];
    #pragma unroll
    for (int c = 0; c < 8; ++c) q8[c] = q[((long)b * C2 + g * 8 + c) * HW + n];

    // ======== phase 1: 25 weights, 5x5 mix over v0 ========
    {
        float w1[25];
        #pragma unroll
        for (int m = 0; m < 25; ++m) w1[m] = wpb1_s[m];
        #pragma unroll
        for (int c = 0; c < 8; ++c) {
            const float qv = q8[c];
            #pragma unroll
            for (int m = 0; m < 25; ++m) w1[m] = fmaf(qv, WK1_s[c * 28 + m], w1[m]);
        }
        const int rh5 = yr < 2 ? yr : (yr > 53 ? yr - 51 : 2);
        const int rw5 = xr < 2 ? xr : (xr > 53 ? xr - 51 : 2);
        #pragma unroll
        for (int i = 0; i < 5; ++i)
            #pragma unroll
            for (int j = 0; j < 5; ++j)
                w1[i * 5 + j] += rpb1_s[(rh5 + i) * 9 + (rw5 + j)];
        float mx = -1e30f;
        #pragma unroll
        for (int m = 0; m < 25; ++m) mx = fmaxf(mx, w1[m]);
        float sm = 0.f;
        #pragma unroll
        for (int m = 0; m < 25; ++m) { w1[m] = __expf(w1[m] - mx); sm += w1[m]; }
        const float r = 1.f / sm;
        #pragma unroll
        for (int m = 0; m < 25; ++m) w1[m] *= r;

        const float* v0 = x + ((long)b * CC + g * 8) * HW;
        float* m0 = mix + ((long)b * CC + g * 8) * HW + n;
        #pragma unroll
        for (int ch = 0; ch < 8; ++ch) {
            float a = 0.f;
            #pragma unroll
            for (int i = 0; i < 5; ++i) {
                const int y = ph + i - 2;
                if ((unsigned)y >= HH) continue;
                #pragma unroll
                for (int j = 0; j < 5; ++j) {
                    const int xx = pw + j - 2;
                    if ((unsigned)xx >= WW) continue;
                    a = fmaf(w1[i * 5 + j], v0[ch * HW + y * WW + xx], a);
                }
            }
            m0[ch * HW] = a;
        }
    }

    __builtin_amdgcn_sched_barrier(0);   // keep phases from merging (register pressure)

    // ======== phase 2: 49 weights, 7x7 mix over v1 ========
    {
        float w2[49];
        #pragma unroll
        for (int m = 0; m < 49; ++m) w2[m] = wpb2_s[m];
        #pragma unroll
        for (int c = 0; c < 8; ++c) {
            const float qv = q8[c];
            #pragma unroll
            for (int m = 0; m < 49; ++m) w2[m] = fmaf(qv, WK2_s[c * 52 + m], w2[m]);
        }
        const int rh7 = yr < 3 ? yr : (yr > 52 ? yr - 49 : 3);
        const int rw7 = xr < 3 ? xr : (xr > 52 ? xr - 49 : 3);
        #pragma unroll
        for (int i = 0; i < 7; ++i)
            #pragma unroll
            for (int j = 0; j < 7; ++j)
                w2[i * 7 + j] += rpb2_s[(rh7 + i) * 13 + (rw7 + j)];
        float mx = -1e30f;
        #pragma unroll
        for (int m = 0; m < 49; ++m) mx = fmaxf(mx, w2[m]);
        float sm = 0.f;
        #pragma unroll
        for (int m = 0; m < 49; ++m) { w2[m] = __expf(w2[m] - mx); sm += w2[m]; }
        const float r = 1.f / sm;
        #pragma unroll
        for (int m = 0; m < 49; ++m) w2[m] *= r;

        const float* v1 = x + ((long)b * CC + 32 + g * 8) * HW;
        float* m1 = mix + ((long)b * CC + 32 + g * 8) * HW + n;
        #pragma unroll
        for (int ch = 0; ch < 8; ++ch) {
            float a = 0.f;
            #pragma unroll
            for (int i = 0; i < 7; ++i) {
                const int y = ph + i - 3;
                if ((unsigned)y >= HH) continue;
                #pragma unroll
                for (int j = 0; j < 7; ++j) {
                    const int xx = pw + j - 3;
                    if ((unsigned)xx >= WW) continue;
                    a = fmaf(w2[i * 7 + j], v1[ch * HW + y * WW + xx], a);
                }
            }
            m1[ch * HW] = a;
        }
    }
}

// ---------------- final: 64x64 channel matmul + bn + lepe add ----------------
// register-tiled: each thread owns 2 pixels x 32 outputs.
__global__ __launch_bounds__(256) void final_k(const float* __restrict__ mix,
                                               const float* __restrict__ dy_w,
                                               const float* __restrict__ s,
                                               const float* __restrict__ bb,
                                               float* __restrict__ out) {
    __shared__ float w_s[64 * 64];      // transposed: w_s[i*64+o] = dy_w[o*64+i]
    const int tid = threadIdx.x;
    const int b = blockIdx.y;
    for (int i = tid; i < 4096; i += 256) w_s[(i & 63) * 64 + (i >> 6)] = dy_w[i];
    __syncthreads();
    const int ob = (tid >> 7) * 32;                 // wave-uniform output half
    const int p0 = blockIdx.x * 256 + (tid & 127);
    const int p1 = p0 + 128;
    const bool v0 = p0 < HW, v1 = p1 < HW;
    const float* mp = mix + (long)b * CC * HW;
    float acc0[32], acc1[32];
    #pragma unroll
    for (int o = 0; o < 32; ++o) { acc0[o] = 0.f; acc1[o] = 0.f; }
    for (int i = 0; i < 64; ++i) {
        const float mv0 = v0 ? mp[i * HW + p0] : 0.f;
        const float mv1 = v1 ? mp[i * HW + p1] : 0.f;
        const float* wr = w_s + i * 64 + ob;
        #pragma unroll
        for (int o = 0; o < 32; ++o) {
            const float wv = wr[o];
            acc0[o] = fmaf(wv, mv0, acc0[o]);
            acc1[o] = fmaf(wv, mv1, acc1[o]);
        }
    }
    float* op = out + (long)b * CC * HW;
    if (v0) {
        #pragma unroll
        for (int o = 0; o < 32; ++o) {
            const long idx = (long)(ob + o) * HW + p0;
            op[idx] = fmaf(acc0[o], s[ob + o], bb[ob + o]) + op[idx];
        }
    }
    if (v1) {
        #pragma unroll
        for (int o = 0; o < 32; ++o) {
            const long idx = (long)(ob + o) * HW + p1;
            op[idx] = fmaf(acc1[o], s[ob + o], bb[ob + o]) + op[idx];
        }
    }
}

extern "C" void kernel_launch(void* const* d_in, const int* in_sizes, int n_in,
                              void* d_out, int out_size, void* d_ws, size_t ws_size,
                              hipStream_t stream) {
    const float* x       = (const float*)d_in[0];
    const float* lepe_w  = (const float*)d_in[1];
    const float* lepe_b  = (const float*)d_in[2];
    const float* lepe_s  = (const float*)d_in[3];
    const float* lepe_bb = (const float*)d_in[4];
    const float* wq_w    = (const float*)d_in[5];
    const float* wq_s    = (const float*)d_in[6];
    const float* wq_bb   = (const float*)d_in[7];
    const float* wk_w    = (const float*)d_in[8];
    const float* wk_s    = (const float*)d_in[9];
    const float* wk_bb   = (const float*)d_in[10];
    const float* wp_w    = (const float*)d_in[11];
    const float* wp_b    = (const float*)d_in[12];
    const float* rpb1    = (const float*)d_in[13];
    const float* rpb2    = (const float*)d_in[14];
    const float* dy_w    = (const float*)d_in[15];
    const float* dy_s    = (const float*)d_in[16];
    const float* dy_bb   = (const float*)d_in[17];
    float* out = (float*)d_out;

    float* ws     = (float*)d_ws;
    float* q_ws   = ws;                               // 32*32*3136 = 3211264
    float* WK_ws  = q_ws + 32 * 32 * HW;              // 128*640    = 81920
    float* mix_ws = WK_ws + 128 * 640;                // 32*64*3136 = 6422528

    const int nTiles = (HW + 255) / 256;              // 13

    lepe_k<<<dim3(2048 * 784 / 256), 256, 0, stream>>>(x, lepe_w, lepe_b, lepe_s, lepe_bb, out);
    q_k<<<dim3(nTiles, BB), 256, 0, stream>>>(x, wq_w, wq_s, wq_bb, q_ws);
    prep_k<<<dim3(BB), 256, 0, stream>>>(x, wk_w, wk_s, wk_bb, wp_w, WK_ws);
    attnmix_k<<<dim3(nTiles, BB * 4), 256, 0, stream>>>(x, q_ws, WK_ws, wp_b, rpb1, rpb2, mix_ws);
    final_k<<<dim3(nTiles, BB), 256, 0, stream>>>(mix_ws, dy_w, dy_s, dy_bb, out);
}

// Round 4
// 271.821 us; speedup vs baseline: 2.7985x; 1.6168x over previous
//
#include <hip/hip_runtime.h>

#define BB 32
#define CC 64
#define C2 32
#define HH 56
#define WW 56
#define HW 3136

// ---------------- lepe: depthwise 7x7 conv + bias + bn -> d_out ----------------
__global__ __launch_bounds__(256) void lepe_k(const float* __restrict__ x,
                                              const float* __restrict__ wt,
                                              const float* __restrict__ b,
                                              const float* __restrict__ s,
                                              const float* __restrict__ bb,
                                              float* __restrict__ out) {
    const int t = blockIdx.x * 256 + threadIdx.x;      // 2048*784 threads exactly
    const int q = t % 784;
    const int bc = t / 784;
    const int c = bc & 63;
    const int r = q / 14;
    const int c4 = (q % 14) * 4;
    const float* xp = x + (long)bc * HW;
    float acc0 = 0.f, acc1 = 0.f, acc2 = 0.f, acc3 = 0.f;
    #pragma unroll
    for (int i = 0; i < 7; ++i) {
        const int y = r + i - 3;
        if ((unsigned)y >= HH) continue;
        float w7[7];
        #pragma unroll
        for (int j = 0; j < 7; ++j) w7[j] = wt[c * 49 + i * 7 + j];
        const float4* row = reinterpret_cast<const float4*>(xp + y * WW + c4 - 4);
        float4 A = make_float4(0.f, 0.f, 0.f, 0.f);
        float4 Cv = make_float4(0.f, 0.f, 0.f, 0.f);
        if (c4 != 0) A = row[0];
        const float4 Bv = row[1];
        if (c4 != 52) Cv = row[2];
        const float w12[12] = {A.x, A.y, A.z, A.w, Bv.x, Bv.y, Bv.z, Bv.w, Cv.x, Cv.y, Cv.z, Cv.w};
        #pragma unroll
        for (int j = 0; j < 7; ++j) {
            acc0 = fmaf(w12[j + 1], w7[j], acc0);
            acc1 = fmaf(w12[j + 2], w7[j], acc1);
            acc2 = fmaf(w12[j + 3], w7[j], acc2);
            acc3 = fmaf(w12[j + 4], w7[j], acc3);
        }
    }
    const float bc_ = b[c], sc = s[c], bbc = bb[c];
    float* op = out + (long)bc * HW + r * WW + c4;
    op[0] = (acc0 + bc_) * sc + bbc;
    op[1] = (acc1 + bc_) * sc + bbc;
    op[2] = (acc2 + bc_) * sc + bbc;
    op[3] = (acc3 + bc_) * sc + bbc;
}

// ---------------- q: 32x32 channel matmul + bn, *SCALE ----------------
__global__ __launch_bounds__(256) void q_k(const float* __restrict__ x,
                                           const float* __restrict__ wq,
                                           const float* __restrict__ s,
                                           const float* __restrict__ bb,
                                           float* __restrict__ q) {
    __shared__ float wsm[32 * 32];      // transposed: wsm[i*32+o] = wq[o*32+i]
    const int b = blockIdx.y;
    const int tid = threadIdx.x;
    for (int i = tid; i < 1024; i += 256) wsm[(i & 31) * 32 + (i >> 5)] = wq[i];
    __syncthreads();
    const int n = blockIdx.x * 256 + tid;
    if (n >= HW) return;
    const float* xp = x + (long)b * CC * HW;   // first 32 channels
    float acc[32];
    #pragma unroll
    for (int o = 0; o < 32; ++o) acc[o] = 0.f;
    for (int i = 0; i < 32; ++i) {
        const float xv = xp[i * HW + n];
        #pragma unroll
        for (int o = 0; o < 32; ++o) acc[o] = fmaf(wsm[i * 32 + o], xv, acc[o]);
    }
    float* qp = q + (long)b * C2 * HW + n;
    #pragma unroll
    for (int o = 0; o < 32; ++o)
        qp[o * HW] = (acc[o] * s[o] + bb[o]) * 0.25f;
}

// ---------------- prep: pool(8x8 mean) -> wk matmul+bn -> WK = wp * kg^T ----------------
// One block per (b,g): 128 blocks. Pool recomputed per group (cheap, 4x parallelism).
// Output per bg: WK1[c][28] (25 used) then WK2[c][52] (49 used), zero-padded, 640 floats.
__global__ __launch_bounds__(256) void prep_k(const float* __restrict__ x,
                                              const float* __restrict__ wk,
                                              const float* __restrict__ wks,
                                              const float* __restrict__ wkb,
                                              const float* __restrict__ wp_w,
                                              float* __restrict__ WK) {
    __shared__ float p_s[32 * 49];
    __shared__ float kg_s[8 * 49];
    const int b = blockIdx.x >> 2;
    const int g = blockIdx.x & 3;
    const int tid = threadIdx.x;
    for (int idx = tid; idx < 1568; idx += 256) {
        const int i = idx / 49, l = idx % 49;
        const int py = l / 7, px = l % 7;
        const float4* xp4 = reinterpret_cast<const float4*>(
            x + ((long)(b * CC + 32 + i)) * HW + py * 8 * WW + px * 8);
        float4 sA = make_float4(0.f, 0.f, 0.f, 0.f);
        float4 sB = make_float4(0.f, 0.f, 0.f, 0.f);
        #pragma unroll
        for (int y = 0; y < 8; ++y) {
            const float4 a = xp4[y * 14];
            const float4 c = xp4[y * 14 + 1];
            sA.x += a.x; sA.y += a.y; sA.z += a.z; sA.w += a.w;
            sB.x += c.x; sB.y += c.y; sB.z += c.z; sB.w += c.w;
        }
        p_s[idx] = (sA.x + sA.y + sA.z + sA.w + sB.x + sB.y + sB.z + sB.w) * (1.f / 64.f);
    }
    __syncthreads();
    for (int idx = tid; idx < 392; idx += 256) {       // 8 outputs of this group x 49
        const int o8 = idx / 49, l = idx % 49;
        const int o = g * 8 + o8;
        float acc = 0.f;
        #pragma unroll
        for (int i = 0; i < 32; ++i) acc = fmaf(wk[o * 32 + i], p_s[i * 49 + l], acc);
        kg_s[idx] = acc * wks[o] + wkb[o];
    }
    __syncthreads();
    for (int idx = tid; idx < 640; idx += 256) {       // 8 c x 80 slots
        const int c = idx / 80, slot = idx % 80;
        float acc = 0.f;
        int m = -1;
        if (slot < 28) { if (slot < 25) m = slot; }
        else           { if (slot < 77) m = 25 + (slot - 28); }
        if (m >= 0) {
            const float* kp = kg_s + c * 49;
            #pragma unroll
            for (int l = 0; l < 49; ++l) acc = fmaf(wp_w[m * 49 + l], kp[l], acc);
        }
        const long base = (long)blockIdx.x * 640;
        if (slot < 28) WK[base + c * 28 + slot] = acc;
        else           WK[base + 224 + c * 52 + (slot - 28)] = acc;
    }
}

// ---------------- fused attention (q -> wm via WK -> +rpb -> softmax) + dyn_mix ----------------
// Two phases (25-weight / 49-weight). Mix loops are tap-outer / channel-inner:
// 8 independent accumulators, loads use immediate offsets off per-channel bases.
__global__ __launch_bounds__(256) void attnmix_k(const float* __restrict__ x,
                                                 const float* __restrict__ q,
                                                 const float* __restrict__ WK,
                                                 const float* __restrict__ wp_b,
                                                 const float* __restrict__ rpb1,
                                                 const float* __restrict__ rpb2,
                                                 float* __restrict__ mix) {
    __shared__ float WK1_s[8 * 28];     // [c][28], pad zeroed
    __shared__ float WK2_s[8 * 52];     // [c][52], pad zeroed
    __shared__ float wpb1_s[25];
    __shared__ float wpb2_s[49];
    __shared__ float rpb1_s[81];
    __shared__ float rpb2_s[169];
    const int tid = threadIdx.x;
    const int bg = blockIdx.y;
    const int g = bg & 3, b = bg >> 2;
    {
        const float* wkp = WK + (long)bg * 640;
        for (int i = tid; i < 224; i += 256) WK1_s[i] = wkp[i];
        for (int i = tid; i < 416; i += 256) WK2_s[i] = wkp[224 + i];
    }
    if (tid < 25) wpb1_s[tid] = wp_b[tid];
    if (tid >= 32 && tid < 81) wpb2_s[tid - 32] = wp_b[25 + tid - 32];
    if (tid < 81) rpb1_s[tid] = rpb1[g * 81 + tid];
    if (tid < 169) rpb2_s[tid] = rpb2[g * 169 + tid];
    __syncthreads();
    const int n = blockIdx.x * 256 + tid;
    if (n >= HW) return;

    const int ph = n / WW, pw = n % WW;
    const int yr = HH - 1 - ph, xr = WW - 1 - pw;

    float q8[8];
    #pragma unroll
    for (int c = 0; c < 8; ++c) q8[c] = q[((long)b * C2 + g * 8 + c) * HW + n];

    // ======== phase 1: 25 weights, 5x5 mix over v0 ========
    {
        float w1[25];
        #pragma unroll
        for (int m = 0; m < 25; ++m) w1[m] = wpb1_s[m];
        #pragma unroll
        for (int c = 0; c < 8; ++c) {
            const float qv = q8[c];
            #pragma unroll
            for (int m = 0; m < 25; ++m) w1[m] = fmaf(qv, WK1_s[c * 28 + m], w1[m]);
        }
        const int rh5 = yr < 2 ? yr : (yr > 53 ? yr - 51 : 2);
        const int rw5 = xr < 2 ? xr : (xr > 53 ? xr - 51 : 2);
        #pragma unroll
        for (int i = 0; i < 5; ++i)
            #pragma unroll
            for (int j = 0; j < 5; ++j)
                w1[i * 5 + j] += rpb1_s[(rh5 + i) * 9 + (rw5 + j)];
        float mx = -1e30f;
        #pragma unroll
        for (int m = 0; m < 25; ++m) mx = fmaxf(mx, w1[m]);
        float sm = 0.f;
        #pragma unroll
        for (int m = 0; m < 25; ++m) { w1[m] = __expf(w1[m] - mx); sm += w1[m]; }
        const float r = 1.f / sm;
        #pragma unroll
        for (int m = 0; m < 25; ++m) w1[m] *= r;

        const float* vb = x + ((long)b * CC + g * 8) * HW + n;   // pixel-n base, ch stride HW
        float acc[8];
        #pragma unroll
        for (int ch = 0; ch < 8; ++ch) acc[ch] = 0.f;
        #pragma unroll
        for (int i = 0; i < 5; ++i) {
            const int y = ph + i - 2;
            if ((unsigned)y >= HH) continue;
            #pragma unroll
            for (int j = 0; j < 5; ++j) {
                const int xx = pw + j - 2;
                if ((unsigned)xx >= WW) continue;
                const int off = (i - 2) * WW + (j - 2);
                const float wv = w1[i * 5 + j];
                #pragma unroll
                for (int ch = 0; ch < 8; ++ch)
                    acc[ch] = fmaf(wv, vb[ch * HW + off], acc[ch]);
            }
        }
        float* m0 = mix + ((long)b * CC + g * 8) * HW + n;
        #pragma unroll
        for (int ch = 0; ch < 8; ++ch) m0[ch * HW] = acc[ch];
    }

    __builtin_amdgcn_sched_barrier(0);   // keep phases from merging (register pressure)

    // ======== phase 2: 49 weights, 7x7 mix over v1 ========
    {
        float w2[49];
        #pragma unroll
        for (int m = 0; m < 49; ++m) w2[m] = wpb2_s[m];
        #pragma unroll
        for (int c = 0; c < 8; ++c) {
            const float qv = q8[c];
            #pragma unroll
            for (int m = 0; m < 49; ++m) w2[m] = fmaf(qv, WK2_s[c * 52 + m], w2[m]);
        }
        const int rh7 = yr < 3 ? yr : (yr > 52 ? yr - 49 : 3);
        const int rw7 = xr < 3 ? xr : (xr > 52 ? xr - 49 : 3);
        #pragma unroll
        for (int i = 0; i < 7; ++i)
            #pragma unroll
            for (int j = 0; j < 7; ++j)
                w2[i * 7 + j] += rpb2_s[(rh7 + i) * 13 + (rw7 + j)];
        float mx = -1e30f;
        #pragma unroll
        for (int m = 0; m < 49; ++m) mx = fmaxf(mx, w2[m]);
        float sm = 0.f;
        #pragma unroll
        for (int m = 0; m < 49; ++m) { w2[m] = __expf(w2[m] - mx); sm += w2[m]; }
        const float r = 1.f / sm;
        #pragma unroll
        for (int m = 0; m < 49; ++m) w2[m] *= r;

        const float* vb = x + ((long)b * CC + 32 + g * 8) * HW + n;
        float acc[8];
        #pragma unroll
        for (int ch = 0; ch < 8; ++ch) acc[ch] = 0.f;
        #pragma unroll
        for (int i = 0; i < 7; ++i) {
            const int y = ph + i - 3;
            if ((unsigned)y >= HH) continue;
            #pragma unroll
            for (int j = 0; j < 7; ++j) {
                const int xx = pw + j - 3;
                if ((unsigned)xx >= WW) continue;
                const int off = (i - 3) * WW + (j - 3);
                const float wv = w2[i * 7 + j];
                #pragma unroll
                for (int ch = 0; ch < 8; ++ch)
                    acc[ch] = fmaf(wv, vb[ch * HW + off], acc[ch]);
            }
        }
        float* m1 = mix + ((long)b * CC + 32 + g * 8) * HW + n;
        #pragma unroll
        for (int ch = 0; ch < 8; ++ch) m1[ch * HW] = acc[ch];
    }
}

// ---------------- final: 64x64 channel matmul + bn + lepe add ----------------
// float2 pixel pairs: each thread owns 2 consecutive pixels x 32 outputs.
__global__ __launch_bounds__(256) void final_k(const float* __restrict__ mix,
                                               const float* __restrict__ dy_w,
                                               const float* __restrict__ s,
                                               const float* __restrict__ bb,
                                               float* __restrict__ out) {
    __shared__ float w_s[64 * 64];      // transposed: w_s[i*64+o] = dy_w[o*64+i]
    const int tid = threadIdx.x;
    const int b = blockIdx.y;
    for (int i = tid; i < 4096; i += 256) w_s[(i & 63) * 64 + (i >> 6)] = dy_w[i];
    __syncthreads();
    const int ob = (tid >> 7) * 32;                 // wave-uniform output half
    const int p2 = blockIdx.x * 128 + (tid & 127);  // float2 pixel-pair index, HW/2=1568
    if (p2 >= 1568) return;
    const float2* mp = reinterpret_cast<const float2*>(mix + (long)b * CC * HW);
    float accx[32], accy[32];
    #pragma unroll
    for (int o = 0; o < 32; ++o) { accx[o] = 0.f; accy[o] = 0.f; }
    for (int i = 0; i < 64; ++i) {
        const float2 mv = mp[i * 1568 + p2];
        const float* wr = w_s + i * 64 + ob;
        #pragma unroll
        for (int o = 0; o < 32; ++o) {
            const float wv = wr[o];
            accx[o] = fmaf(wv, mv.x, accx[o]);
            accy[o] = fmaf(wv, mv.y, accy[o]);
        }
    }
    float2* op = reinterpret_cast<float2*>(out + (long)b * CC * HW);
    #pragma unroll
    for (int o = 0; o < 32; ++o) {
        const long idx = (long)(ob + o) * 1568 + p2;
        const float2 prev = op[idx];
        float2 res;
        res.x = fmaf(accx[o], s[ob + o], bb[ob + o]) + prev.x;
        res.y = fmaf(accy[o], s[ob + o], bb[ob + o]) + prev.y;
        op[idx] = res;
    }
}

extern "C" void kernel_launch(void* const* d_in, const int* in_sizes, int n_in,
                              void* d_out, int out_size, void* d_ws, size_t ws_size,
                              hipStream_t stream) {
    const float* x       = (const float*)d_in[0];
    const float* lepe_w  = (const float*)d_in[1];
    const float* lepe_b  = (const float*)d_in[2];
    const float* lepe_s  = (const float*)d_in[3];
    const float* lepe_bb = (const float*)d_in[4];
    const float* wq_w    = (const float*)d_in[5];
    const float* wq_s    = (const float*)d_in[6];
    const float* wq_bb   = (const float*)d_in[7];
    const float* wk_w    = (const float*)d_in[8];
    const float* wk_s    = (const float*)d_in[9];
    const float* wk_bb   = (const float*)d_in[10];
    const float* wp_w    = (const float*)d_in[11];
    const float* wp_b    = (const float*)d_in[12];
    const float* rpb1    = (const float*)d_in[13];
    const float* rpb2    = (const float*)d_in[14];
    const float* dy_w    = (const float*)d_in[15];
    const float* dy_s    = (const float*)d_in[16];
    const float* dy_bb   = (const float*)d_in[17];
    float* out = (float*)d_out;

    float* ws     = (float*)d_ws;
    float* q_ws   = ws;                               // 32*32*3136 = 3211264
    float* WK_ws  = q_ws + 32 * 32 * HW;              // 128*640    = 81920
    float* mix_ws = WK_ws + 128 * 640;                // 32*64*3136 = 6422528

    const int nTiles = (HW + 255) / 256;              // 13

    lepe_k<<<dim3(2048 * 784 / 256), 256, 0, stream>>>(x, lepe_w, lepe_b, lepe_s, lepe_bb, out);
    q_k<<<dim3(nTiles, BB), 256, 0, stream>>>(x, wq_w, wq_s, wq_bb, q_ws);
    prep_k<<<dim3(BB * 4), 256, 0, stream>>>(x, wk_w, wk_s, wk_bb, wp_w, WK_ws);
    attnmix_k<<<dim3(nTiles, BB * 4), 256, 0, stream>>>(x, q_ws, WK_ws, wp_b, rpb1, rpb2, mix_ws);
    final_k<<<dim3(13, BB), 256, 0, stream>>>(mix_ws, dy_w, dy_s, dy_bb, out);
}